// Round 13
// baseline (103.951 us; speedup 1.0000x reference)
//
#include <hip/hip_runtime.h>

// ImprovedBilateralFilter3D — 96^3 fp32. CALIBRATION ROUND (resubmit; r12
// hit a broker timeout): best-measured kernel (r6: 71.2 us total) launched
// 3x back-to-back to separate harness floor F from kernel time K:
//   dur_us = F + 3K.
// Evidence r3-r11: dur_us pinned at 71-77 regardless of LDS reads
// (216->36), barriers (2->1->0), occupancy (12->32 waves/CU) — consistent
// with K ~= 10 us, F ~= 60 us (41 us poison fill + many small dispatches).
//
// Kernel = r6 exactly: 32x4x4 tile; stage A LDS vol tile (halo 2);
// stage B separable Sobel plane-sweep -> packed float4{gh,gw,gd,val};
// stage C bilateral, 2 voxels/thread (z, z+2), 45 ds_read_b128, __expf.

#define NV 96
#define NV2 (NV * NV)

#define TX 32
#define TY 4
#define TZ 4
#define VX (TX + 4)  // 36
#define VY (TY + 4)  // 8
#define VZ (TZ + 4)  // 8
#define GX (TX + 2)  // 34
#define GY (TY + 2)  // 6
#define GZ (TZ + 2)  // 6
#define NVOL (VX * VY * VZ)  // 2304

__global__ __launch_bounds__(256) void fused_bilateral_kernel(
    const float* __restrict__ vol, float* __restrict__ out) {
    __shared__ float sv[VZ][VY][VX];   // raw volume, zero-padded
    __shared__ float4 sq[GZ][GY][GX];  // {gh, gw, gd, val}

    const int X0 = blockIdx.x * TX;
    const int Y0 = blockIdx.y * TY;
    const int Z0 = blockIdx.z * TZ;
    const int t = threadIdx.x;

    // ---- Stage A: volume tile + halo 2, zero outside global bounds ----
    for (int li = t; li < NVOL; li += 256) {
        int lx = li % VX;
        int lyz = li / VX;
        int ly = lyz % VY;
        int lz = lyz / VY;
        int gx = X0 - 2 + lx;
        int gy = Y0 - 2 + ly;
        int gz = Z0 - 2 + lz;
        float v = 0.0f;
        if (gx >= 0 && gx < NV && gy >= 0 && gy < NV && gz >= 0 && gz < NV)
            v = vol[gz * NV2 + gy * NV + gx];
        sv[lz][ly][lx] = v;
    }
    __syncthreads();

    // ---- Stage B: separable Sobel, z plane-sweep ----
    if (t < GX * GY) {
        const int gx_ = t % GX;
        const int gy_ = t / GX;
        float s0 = 0.f, s1 = 0.f, s2 = 0.f;  // sm_y (x) sm_x per plane
        float w0 = 0.f, w1 = 0.f, w2 = 0.f;  // dy (x) sm_x
        float u0 = 0.f, u1 = 0.f, u2 = 0.f;  // sm_y (x) dx
        float v11p = 0.f;                    // prev-plane center value
#pragma unroll
        for (int p = 0; p < VZ; ++p) {
            float a00 = sv[p][gy_ + 0][gx_ + 0];
            float a01 = sv[p][gy_ + 0][gx_ + 1];
            float a02 = sv[p][gy_ + 0][gx_ + 2];
            float a10 = sv[p][gy_ + 1][gx_ + 0];
            float a11 = sv[p][gy_ + 1][gx_ + 1];
            float a12 = sv[p][gy_ + 1][gx_ + 2];
            float a20 = sv[p][gy_ + 2][gx_ + 0];
            float a21 = sv[p][gy_ + 2][gx_ + 1];
            float a22 = sv[p][gy_ + 2][gx_ + 2];
            float r0 = 0.25f * a00 + 0.5f * a01 + 0.25f * a02;
            float r1 = 0.25f * a10 + 0.5f * a11 + 0.25f * a12;
            float r2 = 0.25f * a20 + 0.5f * a21 + 0.25f * a22;
            float sxy = 0.25f * r0 + 0.5f * r1 + 0.25f * r2;  // sm sm
            float dyx = r0 - r2;                              // dy sm
            float dx0 = a00 - a02;
            float dx1 = a10 - a12;
            float dx2 = a20 - a22;
            float dxs = 0.25f * dx0 + 0.5f * dx1 + 0.25f * dx2;  // sm dx
            s0 = s1; s1 = s2; s2 = sxy;
            w0 = w1; w1 = w2; w2 = dyx;
            u0 = u1; u1 = u2; u2 = dxs;
            if (p >= 2) {
                float gh = s0 - s2;                              // dz
                float gw = 0.25f * w0 + 0.5f * w1 + 0.25f * w2;  // sm_z dy
                float gd = 0.25f * u0 + 0.5f * u1 + 0.25f * u2;  // sm_z dx
                sq[p - 2][gy_][gx_] = make_float4(gh, gw, gd, v11p);
            }
            v11p = a11;
        }
    }
    __syncthreads();

    // ---- Stage C: bilateral, 2 output voxels per thread (z and z+2) ----
    const int tx = t & 31;
    const int ty = (t >> 5) & 3;
    const int tzh = t >> 7;  // 0..1

    const float inv2sd = 1.0f / (2.0f * 120.0f * 120.0f);
    const float inv2sr = 1.0f / (2.0f * 1.2f * 1.2f);

    const int ox = X0 + tx;
    const int oy = Y0 + ty;
    const int oz0 = Z0 + tzh;
    const int oz1 = oz0 + 2;

    const float4 c0 = sq[tzh + 1][ty + 1][tx + 1];
    const float4 c1 = sq[tzh + 3][ty + 1][tx + 1];

    int nx[3], ny[3], nz[5];
#pragma unroll
    for (int d = 0; d < 3; ++d) {
        nx[d] = min(max(ox + d - 1, 0), NV - 1) - (X0 - 1);
        ny[d] = min(max(oy + d - 1, 0), NV - 1) - (Y0 - 1);
    }
#pragma unroll
    for (int p = 0; p < 5; ++p)
        nz[p] = min(max(oz0 + p - 1, 0), NV - 1) - (Z0 - 1);

    float num0 = 0.0f, den0 = 0.0f, num1 = 0.0f, den1 = 0.0f;

#pragma unroll
    for (int p = 0; p < 5; ++p) {  // absolute plane oz0-1+p
#pragma unroll
        for (int iy = 0; iy < 3; ++iy) {
#pragma unroll
            for (int ix = 0; ix < 3; ++ix) {
                float4 q = sq[nz[p]][ny[iy]][nx[ix]];
                if (p <= 2) {  // voxel0: dz = p-1
                    const float sdc =
                        (float)((p - 1) * (p - 1) + (iy - 1) * (iy - 1) +
                                (ix - 1) * (ix - 1)) * inv2sd;
                    float a = c0.x - q.x, b = c0.y - q.y, e = c0.z - q.z;
                    float g = a * a + b * b + e * e;
                    float w = __expf(-(sdc + g * inv2sr));
                    num0 += w * q.w;
                    den0 += w;
                }
                if (p >= 2) {  // voxel1: dz = p-3
                    const float sdc =
                        (float)((p - 3) * (p - 3) + (iy - 1) * (iy - 1) +
                                (ix - 1) * (ix - 1)) * inv2sd;
                    float a = c1.x - q.x, b = c1.y - q.y, e = c1.z - q.z;
                    float g = a * a + b * b + e * e;
                    float w = __expf(-(sdc + g * inv2sr));
                    num1 += w * q.w;
                    den1 += w;
                }
            }
        }
    }

    out[oz0 * NV2 + oy * NV + ox] = num0 / fmaxf(den0, 1e-8f);
    out[oz1 * NV2 + oy * NV + ox] = num1 / fmaxf(den1, 1e-8f);
}

extern "C" void kernel_launch(void* const* d_in, const int* in_sizes, int n_in,
                              void* d_out, int out_size, void* d_ws, size_t ws_size,
                              hipStream_t stream) {
    const float* vol = (const float*)d_in[0];
    float* out = (float*)d_out;

    dim3 grid(NV / TX, NV / TY, NV / TZ);  // 3 x 24 x 24 = 1728 blocks
    // CALIBRATION: 3 identical launches -> dur_us = F + 3K. Idempotent
    // (each launch writes the same output), same work every call.
    fused_bilateral_kernel<<<grid, dim3(256), 0, stream>>>(vol, out);
    fused_bilateral_kernel<<<grid, dim3(256), 0, stream>>>(vol, out);
    fused_bilateral_kernel<<<grid, dim3(256), 0, stream>>>(vol, out);
}